// Round 4
// baseline (1095.745 us; speedup 1.0000x reference)
//
#include <hip/hip_runtime.h>
#include <hip/hip_cooperative_groups.h>
#include <stdint.h>

namespace cg = cooperative_groups;

typedef _Float16 f16x8 __attribute__((ext_vector_type(8)));
typedef float f32x4 __attribute__((ext_vector_type(4)));

__device__ __forceinline__ unsigned short f2h(float f) {
  _Float16 h = (_Float16)f;
  return __builtin_bit_cast(unsigned short, h);
}

#if __has_builtin(__builtin_amdgcn_global_load_lds)
#define HAVE_GLL 1
__device__ __forceinline__ void gload_lds16(const void* g, void* l) {
  auto gp = reinterpret_cast<const __attribute__((address_space(1))) void*>(
      reinterpret_cast<uintptr_t>(g));
  auto lp = reinterpret_cast<__attribute__((address_space(3))) void*>(
      reinterpret_cast<uintptr_t>(l));
  __builtin_amdgcn_global_load_lds(gp, lp, 16, 0, 0);
}
#else
#define HAVE_GLL 0
#endif

// ---------------- GEMM core: C[M,N] = A[M,K] * B[N,K]^T (fp16 inputs) ----------------
// 128x128 tile, BK=64, 256 threads (4 waves, 2x2 of 64x64), mfma 16x16x32 f16.
// LDS XOR-swizzled at 16B granularity; staging via global_load_lds(16B).
// PROVEN structure, untouched. Session ledger: R1 8-phase port REGRESSED (custom
// derived waits); R2 softmax fusion REGRESSED (end-of-kernel VALU burst);
// R3 (256,4) launch-bounds NEUTRAL (real occupancy limit = 64 VGPR + ~68 AGPR
// = 132 unified regs -> 3 waves/SIMD class already; lever doesn't exist).
// R4 (this): kernels unchanged; launches fused cooperatively (gap attack).
template <int OUT, int BVU>
__device__ __forceinline__ void gemm_core(unsigned short* __restrict__ As,
                                          unsigned short* __restrict__ Bs,
                                          const unsigned short* __restrict__ A,
                                          const unsigned short* __restrict__ B,
                                          void* __restrict__ Cv, int K, int lda, int ldb,
                                          int ldc, long coff, int m0, int n0, int kbase) {
  int tid = threadIdx.x;
  int wid = tid >> 6, lane = tid & 63;
  int wm = (wid >> 1) * 64, wn = (wid & 1) * 64;
  int rq = lane >> 4, rl = lane & 15;

  f32x4 acc[4][4];
#pragma unroll
  for (int i = 0; i < 4; ++i)
#pragma unroll
    for (int j = 0; j < 4; ++j) acc[i][j] = (f32x4){0.f, 0.f, 0.f, 0.f};

#if HAVE_GLL
  int cg_ = (lane & 7) ^ ((lane >> 3) & 7);  // permuted global chunk -> swizzled LDS
  int rl8 = lane >> 3;                       // row within 8-row group
#endif

  for (int k0 = 0; k0 < K; k0 += 64) {
    long bko;
    if (BVU) {
      int kk = kbase + k0;
      bko = (long)(kk >> 10) * 2097152 + (kk & 1023);
    } else {
      bko = k0;
    }
    __syncthreads();
#if HAVE_GLL
#pragma unroll
    for (int t = 0; t < 4; ++t) {
      int r = wid * 32 + t * 8;  // uniform slab base row
      gload_lds16(&A[(long)(m0 + r + rl8) * lda + k0 + cg_ * 8], &As[r * 64]);
      gload_lds16(&B[(long)(n0 + r + rl8) * ldb + bko + cg_ * 8], &Bs[r * 64]);
    }
#else
#pragma unroll
    for (int it = 0; it < 4; ++it) {
      int idx = tid + it * 256;
      int r = idx >> 3, c = idx & 7;
      int cs = c ^ (r & 7);
      *reinterpret_cast<uint4*>(&As[r * 64 + cs * 8]) =
          *reinterpret_cast<const uint4*>(&A[(long)(m0 + r) * lda + k0 + c * 8]);
      *reinterpret_cast<uint4*>(&Bs[r * 64 + cs * 8]) =
          *reinterpret_cast<const uint4*>(&B[(long)(n0 + r) * ldb + bko + c * 8]);
    }
#endif
    __syncthreads();
#pragma unroll
    for (int ks = 0; ks < 2; ++ks) {
      f16x8 af[4], bfr[4];
      int kc = ks * 4 + rq;
#pragma unroll
      for (int i = 0; i < 4; ++i) {
        int ra = wm + i * 16 + rl;
        af[i] = *reinterpret_cast<const f16x8*>(&As[ra * 64 + ((kc ^ (ra & 7)) << 3)]);
        int rb = wn + i * 16 + rl;
        bfr[i] = *reinterpret_cast<const f16x8*>(&Bs[rb * 64 + ((kc ^ (rb & 7)) << 3)]);
      }
#pragma unroll
      for (int i = 0; i < 4; ++i)
#pragma unroll
        for (int j = 0; j < 4; ++j)
          acc[i][j] = __builtin_amdgcn_mfma_f32_16x16x32_f16(af[i], bfr[j], acc[i][j], 0, 0, 0);
    }
  }

#pragma unroll
  for (int i = 0; i < 4; ++i)
#pragma unroll
    for (int j = 0; j < 4; ++j)
#pragma unroll
      for (int r = 0; r < 4; ++r) {
        int row = m0 + wm + i * 16 + rq * 4 + r;
        int col = n0 + wn + j * 16 + rl;
        float v = acc[i][j][r];
        if (OUT == 1)
          reinterpret_cast<unsigned short*>(Cv)[coff + (long)row * ldc + col] = f2h(v);
        else
          reinterpret_cast<float*>(Cv)[coff + (long)row * ldc + col] = v;
      }
}

// ---------------- w_core: same 128x128xBK64 gemm but staging from RAW fp32 ----------------
__device__ __forceinline__ void w_core(unsigned short* __restrict__ As,
                                       unsigned short* __restrict__ Bs,
                                       const float* __restrict__ A32,
                                       const float* __restrict__ B32,
                                       unsigned short* __restrict__ C,
                                       int lda, int ldb, bool atrans, int m0, int n0) {
  int tid = threadIdx.x;
  int wid = tid >> 6, lane = tid & 63;
  int wm = (wid >> 1) * 64, wn = (wid & 1) * 64;
  int rq = lane >> 4, rl = lane & 15;

  f32x4 acc[4][4];
#pragma unroll
  for (int i = 0; i < 4; ++i)
#pragma unroll
    for (int j = 0; j < 4; ++j) acc[i][j] = (f32x4){0.f, 0.f, 0.f, 0.f};

  for (int k0 = 0; k0 < 512; k0 += 64) {
    __syncthreads();
    if (!atrans) {
#pragma unroll
      for (int it = 0; it < 8; ++it) {
        int idx = it * 256 + tid;
        int r = idx >> 4, kq = idx & 15;
        float4 v = *reinterpret_cast<const float4*>(&A32[(long)(m0 + r) * lda + k0 + kq * 4]);
        ushort4 u;
        u.x = f2h(v.x); u.y = f2h(v.y); u.z = f2h(v.z); u.w = f2h(v.w);
        int cs = (kq >> 1) ^ (r & 7);
        *reinterpret_cast<ushort4*>(&As[r * 64 + cs * 8 + (kq & 1) * 4]) = u;
      }
    } else {
#pragma unroll
      for (int it = 0; it < 32; ++it) {
        int idx = it * 256 + tid;
        int m = idx & 127, d = idx >> 7;  // coalesced over m (128x4B runs)
        float v = A32[(long)(k0 + d) * 512 + m0 + m];
        int cs = (d >> 3) ^ (m & 7);
        As[m * 64 + cs * 8 + (d & 7)] = f2h(v);
      }
    }
#pragma unroll
    for (int it = 0; it < 8; ++it) {
      int idx = it * 256 + tid;
      int r = idx >> 4, kq = idx & 15;
      float4 v = *reinterpret_cast<const float4*>(&B32[(long)(n0 + r) * ldb + k0 + kq * 4]);
      ushort4 u;
      u.x = f2h(v.x); u.y = f2h(v.y); u.z = f2h(v.z); u.w = f2h(v.w);
      int cs = (kq >> 1) ^ (r & 7);
      *reinterpret_cast<ushort4*>(&Bs[r * 64 + cs * 8 + (kq & 1) * 4]) = u;
    }
    __syncthreads();
#pragma unroll
    for (int ks = 0; ks < 2; ++ks) {
      f16x8 af[4], bfr[4];
      int kc = ks * 4 + rq;
#pragma unroll
      for (int i = 0; i < 4; ++i) {
        int ra = wm + i * 16 + rl;
        af[i] = *reinterpret_cast<const f16x8*>(&As[ra * 64 + ((kc ^ (ra & 7)) << 3)]);
        int rb = wn + i * 16 + rl;
        bfr[i] = *reinterpret_cast<const f16x8*>(&Bs[rb * 64 + ((kc ^ (rb & 7)) << 3)]);
      }
#pragma unroll
      for (int i = 0; i < 4; ++i)
#pragma unroll
        for (int j = 0; j < 4; ++j)
          acc[i][j] = __builtin_amdgcn_mfma_f32_16x16x32_f16(af[i], bfr[j], acc[i][j], 0, 0, 0);
    }
  }

#pragma unroll
  for (int i = 0; i < 4; ++i)
#pragma unroll
    for (int j = 0; j < 4; ++j)
#pragma unroll
      for (int r = 0; r < 4; ++r) {
        int row = m0 + wm + i * 16 + rq * 4 + r;
        int col = n0 + wn + j * 16 + rl;
        C[(long)row * 512 + col] = f2h(acc[i][j][r]);
      }
}

// ================= per-stage bodies (verbatim from the R0/R3 kernels) =================

// S0/L1: (c,w) of grid (8,288). w>=32: x fp32->fp16 convert; w<16: Gt fold;
// w in [16,32): Wvut fold (A transposed).
__device__ __forceinline__ void dev_wsetup(int c, int w, const float* __restrict__ x,
    const float* __restrict__ Wq, const float* __restrict__ Wk,
    const float* __restrict__ Wv, const float* __restrict__ Wu,
    unsigned short* __restrict__ Xh, unsigned short* __restrict__ Gt,
    unsigned short* __restrict__ Wvut, unsigned short* As, unsigned short* Bs) {
  if (w >= 32) {
    int i = ((w - 32) * 8 + c) * 256 + threadIdx.x;
    float4 v = reinterpret_cast<const float4*>(x)[i];
    ushort4 u;
    u.x = f2h(v.x); u.y = f2h(v.y); u.z = f2h(v.z); u.w = f2h(v.w);
    reinterpret_cast<ushort4*>(Xh)[i] = u;
    return;
  }
  const float *A32, *B32;
  unsigned short* C;
  int lda;
  bool atrans;
  int t;
  if (w < 16) {
    A32 = Wq + c * 512; B32 = Wk + c * 512; C = Gt + (long)c * 262144;
    lda = 4096; atrans = false; t = w;
  } else {
    A32 = Wu + (long)c * 262144; B32 = Wv + c * 512; C = Wvut + (long)c * 262144;
    lda = 512; atrans = true; t = w - 16;
  }
  w_core(As, Bs, A32, B32, C, lda, 4096, atrans, (t >> 2) * 128, (t & 3) * 128);
}

// S1/L2: (c,w) of grid (8,256). T + VU projections.
__device__ __forceinline__ void dev_tv(int c, int w, const unsigned short* __restrict__ X,
    const unsigned short* __restrict__ Gt, const unsigned short* __restrict__ Wvut,
    unsigned short* __restrict__ T, unsigned short* __restrict__ VUt,
    unsigned short* As, unsigned short* Bs) {
  const unsigned short *A, *B;
  unsigned short* C;
  long coff;
  int m0, n0;
  if (w < 128) {
    A = X; B = Gt + (long)c * 262144; C = T;
    coff = (long)c * 512; m0 = (w >> 2) * 128; n0 = (w & 3) * 128;
  } else {
    int wp = w - 128;
    A = Wvut; B = X; C = VUt;
    coff = 0; m0 = (4 * c + (wp & 3)) * 128; n0 = (wp >> 2) * 128;
  }
  gemm_core<1, 0>(As, Bs, A, B, C, 512, 512, 512, 4096, coff, m0, n0, 0);
}

// S2/L3: (c,w) of grid (8,256). P = T.X^T, (b,h) pinned via z = c + 8*(w>>6).
__device__ __forceinline__ void dev_s(int c, int w, const unsigned short* __restrict__ X,
    const unsigned short* __restrict__ T, unsigned short* __restrict__ Pb,
    unsigned short* As, unsigned short* Bs) {
  int z = c + 8 * (w >> 6), t = w & 63;
  int b = z >> 3, h = z & 7;
  gemm_core<1, 0>(As, Bs, T + (long)b * 4194304 + h * 512, X + (long)b * 524288, Pb,
                  512, 4096, 512, 8192, (long)b * 8388608 + h * 1024,
                  (t >> 3) * 128, (t & 7) * 128, 0);
}

// S3/L4: (c,by) of grid (8,1024). softmax per 1024-chunk, in place.
__device__ __forceinline__ void dev_softmax(int c, int by, unsigned short* __restrict__ S) {
  int g = by * 4 + (threadIdx.x >> 6);
  int b = g >> 10, i = g & 1023;
  long base = (long)b * 8388608 + (long)i * 8192 + (long)c * 1024;
  int lane = threadIdx.x & 63;
  f16x8* p = reinterpret_cast<f16x8*>(S + base);
  f16x8 a = p[lane * 2], bb = p[lane * 2 + 1];
  float v[16];
#pragma unroll
  for (int q = 0; q < 8; ++q) { v[q] = (float)a[q]; v[8 + q] = (float)bb[q]; }
  float m = v[0];
#pragma unroll
  for (int q = 1; q < 16; ++q) m = fmaxf(m, v[q]);
#pragma unroll
  for (int o = 32; o; o >>= 1) m = fmaxf(m, __shfl_xor(m, o));
  float s = 0.f;
#pragma unroll
  for (int q = 0; q < 16; ++q) { v[q] = __expf(v[q] - m); s += v[q]; }
#pragma unroll
  for (int o = 32; o; o >>= 1) s += __shfl_xor(s, o);
  float inv = 1.0f / s;
  f16x8 oa, ob;
#pragma unroll
  for (int q = 0; q < 8; ++q) {
    oa[q] = (_Float16)(v[q] * inv);
    ob[q] = (_Float16)(v[8 + q] * inv);
  }
  p[lane * 2] = oa;
  p[lane * 2 + 1] = ob;
}

// S4/L5: (c,w) of grid (8,64). O-partials, fp32 stores.
__device__ __forceinline__ void dev_out(int c, int w, const unsigned short* __restrict__ Pb,
    const unsigned short* __restrict__ VUt, float* __restrict__ Opart,
    unsigned short* As, unsigned short* Bs) {
  int g = c + 8 * (w >> 4);  // 0..31
  int r = w & 15;
  int b = g >> 3, kc = (g >> 1) & 3, ih = g & 1;
  int y = ih * 4 + (r >> 2);  // 0..7  (i-tile)
  int xx = r & 3;             // 0..3  (e-tile)
  gemm_core<0, 1>(As, Bs, Pb + (long)b * 8388608 + kc * 2048, VUt + (long)b * 1024,
                  Opart, 2048, 8192, 4096, 512,
                  (long)kc * 2097152 + (long)b * 524288, y * 128, xx * 128, kc * 2048);
}

// S5/L6: job j of 2048. out = sum of 4 partials, float4 per thread.
__device__ __forceinline__ void dev_reduce(int j, const float* __restrict__ Opart,
                                           float* __restrict__ out) {
  int i = j * 256 + threadIdx.x;
  float4 a = reinterpret_cast<const float4*>(Opart)[i];
  float4 b = reinterpret_cast<const float4*>(Opart + 2097152)[i];
  float4 c = reinterpret_cast<const float4*>(Opart + 4194304)[i];
  float4 d = reinterpret_cast<const float4*>(Opart + 6291456)[i];
  float4 o;
  o.x = (a.x + b.x) + (c.x + d.x);
  o.y = (a.y + b.y) + (c.y + d.y);
  o.z = (a.z + b.z) + (c.z + d.z);
  o.w = (a.w + b.w) + (c.w + d.w);
  reinterpret_cast<float4*>(out)[i] = o;
}

// ==================== R4: cooperative mega-kernel ====================
// 512 blocks x 256 thr = 2 blocks/CU co-resident (regs <=256 via launch_bounds,
// LDS 32 KiB/block -> 64 KiB/CU). Six stages as grid-strided job loops over the
// IDENTICAL bodies above; 5 grid.sync() boundaries replace 5 kernel launches
// (theory: ~10 us/launch gap -> ~60 us total; grid.sync ~3 us each).
// Job stride 512 == 0 mod 8 keeps c = blk&7 fixed per block (XCD pinning kept).
// __threadfence() (agent scope: buffer_wbl2 + inv on gfx950) around each sync
// handles cross-XCD L2 non-coherence for producer->consumer data (G16).
__global__ __launch_bounds__(256, 2) void k_mega(
    const float* __restrict__ x, const float* __restrict__ Wq,
    const float* __restrict__ Wk, const float* __restrict__ Wv,
    const float* __restrict__ Wu, unsigned short* __restrict__ Xbf,
    unsigned short* __restrict__ Gt, unsigned short* __restrict__ Wvut,
    unsigned short* __restrict__ T, unsigned short* __restrict__ Pb,
    unsigned short* __restrict__ VUt, float* __restrict__ Opart,
    float* __restrict__ out) {
  __shared__ unsigned short As[128 * 64];
  __shared__ unsigned short Bs[128 * 64];
  cg::grid_group gg = cg::this_grid();
  const int blk = blockIdx.x;

  // S0: wsetup, 2304 jobs (folds are j<256 -> one fold max per block, balanced)
  for (int j = blk; j < 2304; j += 512)
    dev_wsetup(j & 7, j >> 3, x, Wq, Wk, Wv, Wu, Xbf, Gt, Wvut, As, Bs);
  __threadfence(); gg.sync(); __threadfence();

  // S1: T + VU, 2048 jobs (4 per block)
  for (int j = blk; j < 2048; j += 512)
    dev_tv(j & 7, j >> 3, Xbf, Gt, Wvut, T, VUt, As, Bs);
  __threadfence(); gg.sync(); __threadfence();

  // S2: S-gemm, 2048 jobs (4 per block)
  for (int j = blk; j < 2048; j += 512)
    dev_s(j & 7, j >> 3, Xbf, T, Pb, As, Bs);
  __threadfence(); gg.sync(); __threadfence();

  // S3: softmax, 8192 jobs (16 per block)
  for (int j = blk; j < 8192; j += 512)
    dev_softmax(j & 7, j >> 3, Pb);
  __threadfence(); gg.sync(); __threadfence();

  // S4: O-partials, 512 jobs (exactly 1 per block). Opart aliases T (T dead).
  dev_out(blk & 7, blk >> 3, Pb, VUt, Opart, As, Bs);
  __threadfence(); gg.sync(); __threadfence();

  // S5: reduce, 2048 jobs (4 per block)
  for (int j = blk; j < 2048; j += 512)
    dev_reduce(j, Opart, out);
}

// ==================== fallback path: the proven 6-launch pipeline ====================
__global__ __launch_bounds__(256, 2) void k_wsetup(
    const float* __restrict__ x, const float* __restrict__ Wq, const float* __restrict__ Wk,
    const float* __restrict__ Wv, const float* __restrict__ Wu,
    unsigned short* __restrict__ Xh, unsigned short* __restrict__ Gt,
    unsigned short* __restrict__ Wvut) {
  __shared__ unsigned short As[128 * 64];
  __shared__ unsigned short Bs[128 * 64];
  dev_wsetup(blockIdx.x, blockIdx.y, x, Wq, Wk, Wv, Wu, Xh, Gt, Wvut, As, Bs);
}

__global__ __launch_bounds__(256, 2) void k_gemm_tv(
    const unsigned short* __restrict__ X, const unsigned short* __restrict__ Gt,
    const unsigned short* __restrict__ Wvut, unsigned short* __restrict__ T,
    unsigned short* __restrict__ VUt) {
  __shared__ unsigned short As[128 * 64];
  __shared__ unsigned short Bs[128 * 64];
  dev_tv(blockIdx.x, blockIdx.y, X, Gt, Wvut, T, VUt, As, Bs);
}

__global__ __launch_bounds__(256, 2) void k_gemm_s(
    const unsigned short* __restrict__ X, const unsigned short* __restrict__ T,
    unsigned short* __restrict__ Pb) {
  __shared__ unsigned short As[128 * 64];
  __shared__ unsigned short Bs[128 * 64];
  dev_s(blockIdx.x, blockIdx.y, X, T, Pb, As, Bs);
}

__global__ __launch_bounds__(256) void k_softmax_x(unsigned short* __restrict__ S) {
  dev_softmax(blockIdx.x, blockIdx.y, S);
}

__global__ __launch_bounds__(256, 2) void k_gemm_out(
    const unsigned short* __restrict__ Pb, const unsigned short* __restrict__ VUt,
    float* __restrict__ Opart) {
  __shared__ unsigned short As[128 * 64];
  __shared__ unsigned short Bs[128 * 64];
  dev_out(blockIdx.x, blockIdx.y, Pb, VUt, Opart, As, Bs);
}

__global__ __launch_bounds__(256) void k_reduce(const float* __restrict__ Opart,
                                                float* __restrict__ out) {
  dev_reduce(blockIdx.x, Opart, out);
}

__global__ void k_sentinel(float* out, float v) { out[0] = v; }

extern "C" void kernel_launch(void* const* d_in, const int* in_sizes, int n_in,
                              void* d_out, int out_size, void* d_ws, size_t ws_size,
                              hipStream_t stream) {
  // setup_inputs dict order: x, Wk, Wq, Wv, Wu
  const float* x  = (const float*)d_in[0];
  const float* Wk = (const float*)d_in[1];
  const float* Wq = (const float*)d_in[2];
  const float* Wv = (const float*)d_in[3];
  const float* Wu = (const float*)d_in[4];
  float* out = (float*)d_out;

  const long SZ_X = 4096L * 512;
  const size_t NEED = 150994944;  // 144 MiB (we use 140; 180 verified previously)

  if (ws_size < NEED) {
    hipMemsetAsync(d_out, 0, (size_t)out_size * 4, stream);
    k_sentinel<<<1, 1, 0, stream>>>(out, (float)ws_size);
    return;
  }

  char* p = (char*)d_ws;
  unsigned short* Xbf  = (unsigned short*)p; p += SZ_X * 2;           //  4 MiB
  unsigned short* Wvut = (unsigned short*)p; p += 8L * 512 * 512 * 2; //  4 MiB [h][e][k]
  unsigned short* Gt   = (unsigned short*)p; p += 8L * 512 * 512 * 2; //  4 MiB [h][b'][a]
  unsigned short* T    = (unsigned short*)p; p += 4096L * 4096 * 2;   // 32 MiB [bt][h*512+b']
  unsigned short* Pb   = (unsigned short*)p; p += 4096L * 8192 * 2;   // 64 MiB [b][i][h*1024+j]
  unsigned short* VUt  = (unsigned short*)p;                          // 32 MiB [h*512+e][b*1024+j]
  float* Opart = (float*)T;  // 32 MiB alias: T dead after S-gemm; 4x[4096][512] fp32

  // ---- R4: single cooperative launch (6 kernels -> 1, kill ~10us/launch gaps) ----
  void* kargs[13];
  kargs[0]  = (void*)&x;
  kargs[1]  = (void*)&Wq;
  kargs[2]  = (void*)&Wk;
  kargs[3]  = (void*)&Wv;
  kargs[4]  = (void*)&Wu;
  kargs[5]  = (void*)&Xbf;
  kargs[6]  = (void*)&Gt;
  kargs[7]  = (void*)&Wvut;
  kargs[8]  = (void*)&T;
  kargs[9]  = (void*)&Pb;
  kargs[10] = (void*)&VUt;
  kargs[11] = (void*)&Opart;
  kargs[12] = (void*)&out;
  hipError_t err =
      hipLaunchCooperativeKernel(k_mega, dim3(512), dim3(256), kargs, 0u, stream);
  if (err == hipSuccess) return;

  // ---- fallback: proven 6-launch pipeline (identical bodies) ----
  k_wsetup<<<dim3(8, 288), 256, 0, stream>>>(x, Wq, Wk, Wv, Wu, Xbf, Gt, Wvut);
  k_gemm_tv<<<dim3(8, 256), 256, 0, stream>>>(Xbf, Gt, Wvut, T, VUt);
  k_gemm_s<<<dim3(8, 256), 256, 0, stream>>>(Xbf, T, Pb);
  k_softmax_x<<<dim3(8, 1024), 256, 0, stream>>>(Pb);
  k_gemm_out<<<dim3(8, 64), 256, 0, stream>>>(Pb, VUt, Opart);
  k_reduce<<<2048, 256, 0, stream>>>(Opart, out);
}

// Round 5
// 355.617 us; speedup vs baseline: 3.0812x; 3.0812x over previous
//
#include <hip/hip_runtime.h>
#include <stdint.h>

typedef _Float16 f16x8 __attribute__((ext_vector_type(8)));
typedef float f32x4 __attribute__((ext_vector_type(4)));

__device__ __forceinline__ unsigned short f2h(float f) {
  _Float16 h = (_Float16)f;
  return __builtin_bit_cast(unsigned short, h);
}

#if __has_builtin(__builtin_amdgcn_global_load_lds)
#define HAVE_GLL 1
__device__ __forceinline__ void gload_lds16(const void* g, void* l) {
  auto gp = reinterpret_cast<const __attribute__((address_space(1))) void*>(
      reinterpret_cast<uintptr_t>(g));
  auto lp = reinterpret_cast<__attribute__((address_space(3))) void*>(
      reinterpret_cast<uintptr_t>(l));
  __builtin_amdgcn_global_load_lds(gp, lp, 16, 0, 0);
}
#else
#define HAVE_GLL 0
#endif

// ---------------- GEMM core: C[M,N] = A[M,K] * B[N,K]^T (fp16 inputs) ----------------
// 128x128 tile, BK=64, 256 threads (4 waves, 2x2 of 64x64), mfma 16x16x32 f16.
// LDS XOR-swizzled at 16B granularity; staging via global_load_lds(16B).
// PROVEN structure, untouched. Session ledger:
//   R1 8-phase 256^2 port      REGRESSED (custom derived-waits != m201 template)
//   R2 softmax fold into GEMMs NEUTRAL   (epilogue VALU burst repurchased the savings)
//   R3 launch_bounds (256,4)   NEUTRAL   (132 unified regs -> already 3 waves/SIMD)
//   R4 cooperative mega-kernel DISASTER  (grid.sync + agent fences: L2 inv per
//      boundary, cross-XCD spin barrier -> 1043us. Launch boundaries ARE the
//      cheap global barrier on MI355X.)
// R5: pipeline reverted; k_reduce folded into k_gemm_out via last-arriver
// counter (no spin, deadlock-free); w_core atrans staging vectorized.
// OUT: 0 fp32 store, 1 fp16 store. BVU: B rows live in VUt[h*512+e][b*1024+j].
template <int OUT, int BVU>
__device__ __forceinline__ void gemm_core(unsigned short* __restrict__ As,
                                          unsigned short* __restrict__ Bs,
                                          const unsigned short* __restrict__ A,
                                          const unsigned short* __restrict__ B,
                                          void* __restrict__ Cv, int K, int lda, int ldb,
                                          int ldc, long coff, int m0, int n0, int kbase) {
  int tid = threadIdx.x;
  int wid = tid >> 6, lane = tid & 63;
  int wm = (wid >> 1) * 64, wn = (wid & 1) * 64;
  int rq = lane >> 4, rl = lane & 15;

  f32x4 acc[4][4];
#pragma unroll
  for (int i = 0; i < 4; ++i)
#pragma unroll
    for (int j = 0; j < 4; ++j) acc[i][j] = (f32x4){0.f, 0.f, 0.f, 0.f};

#if HAVE_GLL
  int cg_ = (lane & 7) ^ ((lane >> 3) & 7);  // permuted global chunk -> swizzled LDS
  int rl8 = lane >> 3;                       // row within 8-row group
#endif

  for (int k0 = 0; k0 < K; k0 += 64) {
    long bko;
    if (BVU) {
      int kk = kbase + k0;
      bko = (long)(kk >> 10) * 2097152 + (kk & 1023);
    } else {
      bko = k0;
    }
    __syncthreads();
#if HAVE_GLL
#pragma unroll
    for (int t = 0; t < 4; ++t) {
      int r = wid * 32 + t * 8;  // uniform slab base row
      gload_lds16(&A[(long)(m0 + r + rl8) * lda + k0 + cg_ * 8], &As[r * 64]);
      gload_lds16(&B[(long)(n0 + r + rl8) * ldb + bko + cg_ * 8], &Bs[r * 64]);
    }
#else
#pragma unroll
    for (int it = 0; it < 4; ++it) {
      int idx = tid + it * 256;
      int r = idx >> 3, c = idx & 7;
      int cs = c ^ (r & 7);
      *reinterpret_cast<uint4*>(&As[r * 64 + cs * 8]) =
          *reinterpret_cast<const uint4*>(&A[(long)(m0 + r) * lda + k0 + c * 8]);
      *reinterpret_cast<uint4*>(&Bs[r * 64 + cs * 8]) =
          *reinterpret_cast<const uint4*>(&B[(long)(n0 + r) * ldb + bko + c * 8]);
    }
#endif
    __syncthreads();
#pragma unroll
    for (int ks = 0; ks < 2; ++ks) {
      f16x8 af[4], bfr[4];
      int kc = ks * 4 + rq;
#pragma unroll
      for (int i = 0; i < 4; ++i) {
        int ra = wm + i * 16 + rl;
        af[i] = *reinterpret_cast<const f16x8*>(&As[ra * 64 + ((kc ^ (ra & 7)) << 3)]);
        int rb = wn + i * 16 + rl;
        bfr[i] = *reinterpret_cast<const f16x8*>(&Bs[rb * 64 + ((kc ^ (rb & 7)) << 3)]);
      }
#pragma unroll
      for (int i = 0; i < 4; ++i)
#pragma unroll
        for (int j = 0; j < 4; ++j)
          acc[i][j] = __builtin_amdgcn_mfma_f32_16x16x32_f16(af[i], bfr[j], acc[i][j], 0, 0, 0);
    }
  }

#pragma unroll
  for (int i = 0; i < 4; ++i)
#pragma unroll
    for (int j = 0; j < 4; ++j)
#pragma unroll
      for (int r = 0; r < 4; ++r) {
        int row = m0 + wm + i * 16 + rq * 4 + r;
        int col = n0 + wn + j * 16 + rl;
        float v = acc[i][j][r];
        if (OUT == 1)
          reinterpret_cast<unsigned short*>(Cv)[coff + (long)row * ldc + col] = f2h(v);
        else
          reinterpret_cast<float*>(Cv)[coff + (long)row * ldc + col] = v;
      }
}

// ---------------- w_core: same 128x128xBK64 gemm but staging from RAW fp32 ----------------
// R5: atrans staging vectorized (float4 along contiguous m) — was 32 SCALAR fp32
// loads/thread/K-tile (Common-mistake #2, ~2.5x tax); now 8 float4 loads, same
// swizzled LDS layout. Only the weight-fold launch uses this core.
__device__ __forceinline__ void w_core(unsigned short* __restrict__ As,
                                       unsigned short* __restrict__ Bs,
                                       const float* __restrict__ A32,
                                       const float* __restrict__ B32,
                                       unsigned short* __restrict__ C,
                                       int lda, int ldb, bool atrans, int m0, int n0) {
  int tid = threadIdx.x;
  int wid = tid >> 6, lane = tid & 63;
  int wm = (wid >> 1) * 64, wn = (wid & 1) * 64;
  int rq = lane >> 4, rl = lane & 15;

  f32x4 acc[4][4];
#pragma unroll
  for (int i = 0; i < 4; ++i)
#pragma unroll
    for (int j = 0; j < 4; ++j) acc[i][j] = (f32x4){0.f, 0.f, 0.f, 0.f};

  for (int k0 = 0; k0 < 512; k0 += 64) {
    __syncthreads();
    if (!atrans) {
#pragma unroll
      for (int it = 0; it < 8; ++it) {
        int idx = it * 256 + tid;
        int r = idx >> 4, kq = idx & 15;
        float4 v = *reinterpret_cast<const float4*>(&A32[(long)(m0 + r) * lda + k0 + kq * 4]);
        ushort4 u;
        u.x = f2h(v.x); u.y = f2h(v.y); u.z = f2h(v.z); u.w = f2h(v.w);
        int cs = (kq >> 1) ^ (r & 7);
        *reinterpret_cast<ushort4*>(&As[r * 64 + cs * 8 + (kq & 1) * 4]) = u;
      }
    } else {
      // A element (m,k) at A32[(k0+d)*512 + m0+m]; contiguous in m -> float4.
      // 64 d x 32 m-quads = 2048 jobs / 256 thr = 8 iters; lanes 0..31 share d,
      // cover m 0..127 -> 512B coalesced runs.
#pragma unroll
      for (int it = 0; it < 8; ++it) {
        int idx = it * 256 + tid;
        int d = idx >> 5, mq = (idx & 31) << 2;
        float4 v = *reinterpret_cast<const float4*>(&A32[(long)(k0 + d) * 512 + m0 + mq]);
        float vv[4] = {v.x, v.y, v.z, v.w};
#pragma unroll
        for (int q = 0; q < 4; ++q) {
          int m = mq + q;
          int cs = (d >> 3) ^ (m & 7);
          As[m * 64 + cs * 8 + (d & 7)] = f2h(vv[q]);
        }
      }
    }
#pragma unroll
    for (int it = 0; it < 8; ++it) {
      int idx = it * 256 + tid;
      int r = idx >> 4, kq = idx & 15;
      float4 v = *reinterpret_cast<const float4*>(&B32[(long)(n0 + r) * ldb + k0 + kq * 4]);
      ushort4 u;
      u.x = f2h(v.x); u.y = f2h(v.y); u.z = f2h(v.z); u.w = f2h(v.w);
      int cs = (kq >> 1) ^ (r & 7);
      *reinterpret_cast<ushort4*>(&Bs[r * 64 + cs * 8 + (kq & 1) * 4]) = u;
    }
    __syncthreads();
#pragma unroll
    for (int ks = 0; ks < 2; ++ks) {
      f16x8 af[4], bfr[4];
      int kc = ks * 4 + rq;
#pragma unroll
      for (int i = 0; i < 4; ++i) {
        int ra = wm + i * 16 + rl;
        af[i] = *reinterpret_cast<const f16x8*>(&As[ra * 64 + ((kc ^ (ra & 7)) << 3)]);
        int rb = wn + i * 16 + rl;
        bfr[i] = *reinterpret_cast<const f16x8*>(&Bs[rb * 64 + ((kc ^ (rb & 7)) << 3)]);
      }
#pragma unroll
      for (int i = 0; i < 4; ++i)
#pragma unroll
        for (int j = 0; j < 4; ++j)
          acc[i][j] = __builtin_amdgcn_mfma_f32_16x16x32_f16(af[i], bfr[j], acc[i][j], 0, 0, 0);
    }
  }

#pragma unroll
  for (int i = 0; i < 4; ++i)
#pragma unroll
    for (int j = 0; j < 4; ++j)
#pragma unroll
      for (int r = 0; r < 4; ++r) {
        int row = m0 + wm + i * 16 + rq * 4 + r;
        int col = n0 + wn + j * 16 + rl;
        C[(long)row * 512 + col] = f2h(acc[i][j][r]);
      }
}

#define DECL_LDS \
  __shared__ unsigned short As[128 * 64]; \
  __shared__ unsigned short Bs[128 * 64];

// L1 (setup+folds merged): grid (8, 288).
// w>=32: convert x fp32->fp16; w<16: Gt fold; w in [16,32): Wvut fold (atrans).
__global__ __launch_bounds__(256, 2) void k_wsetup(
    const float* __restrict__ x, const float* __restrict__ Wq, const float* __restrict__ Wk,
    const float* __restrict__ Wv, const float* __restrict__ Wu,
    unsigned short* __restrict__ Xh, unsigned short* __restrict__ Gt,
    unsigned short* __restrict__ Wvut) {
  DECL_LDS
  int c = blockIdx.x, w = blockIdx.y;
  if (w >= 32) {
    int i = ((w - 32) * 8 + c) * 256 + threadIdx.x;
    float4 v = reinterpret_cast<const float4*>(x)[i];
    ushort4 u;
    u.x = f2h(v.x); u.y = f2h(v.y); u.z = f2h(v.z); u.w = f2h(v.w);
    reinterpret_cast<ushort4*>(Xh)[i] = u;
    return;
  }
  const float *A32, *B32;
  unsigned short* C;
  int lda;
  bool atrans;
  int t;
  if (w < 16) {
    A32 = Wq + c * 512; B32 = Wk + c * 512; C = Gt + (long)c * 262144;
    lda = 4096; atrans = false; t = w;
  } else {
    A32 = Wu + (long)c * 262144; B32 = Wv + c * 512; C = Wvut + (long)c * 262144;
    lda = 512; atrans = true; t = w - 16;
  }
  w_core(As, Bs, A32, B32, C, lda, 4096, atrans, (t >> 2) * 128, (t & 3) * 128);
}

// L2: T + VU projections fused, grid (8,256). ONE gemm_core<1,0> call.
// w<128 : T[bt][h*512+b'] = sum_a X[bt,a] * Gt_h[b',a]; h = c (XCD-pinned).
// w>=128: VUt[h*512+e][b*1024+j] = sum_k Wvut_h[e,k] * X[b*1024+j,k].
__global__ __launch_bounds__(256, 2) void k_gemm_tv(
    const unsigned short* __restrict__ X, const unsigned short* __restrict__ Gt,
    const unsigned short* __restrict__ Wvut, unsigned short* __restrict__ T,
    unsigned short* __restrict__ VUt) {
  DECL_LDS
  int c = blockIdx.x, w = blockIdx.y;
  const unsigned short *A, *B;
  unsigned short* C;
  long coff;
  int m0, n0;
  if (w < 128) {
    A = X; B = Gt + (long)c * 262144; C = T;
    coff = (long)c * 512; m0 = (w >> 2) * 128; n0 = (w & 3) * 128;
  } else {
    int wp = w - 128;
    A = Wvut; B = X; C = VUt;
    coff = 0; m0 = (4 * c + (wp & 3)) * 128; n0 = (wp >> 2) * 128;
  }
  gemm_core<1, 0>(As, Bs, A, B, C, 512, 512, 512, 4096, coff, m0, n0, 0);
}

// L3: S-gemm, grid (8,256). z = c + 8*(w>>6) -> (b,h) pinned to XCD h.
// P[b][i][h*1024+j] = sum_b' T[b*1024+i, h*512+b'] * X[b*1024+j, b'].
__global__ __launch_bounds__(256, 2) void k_gemm_s(
    const unsigned short* __restrict__ X, const unsigned short* __restrict__ T,
    unsigned short* __restrict__ Pb) {
  DECL_LDS
  int c = blockIdx.x, w = blockIdx.y;
  int z = c + 8 * (w >> 6), t = w & 63;
  int b = z >> 3, h = z & 7;
  gemm_core<1, 0>(As, Bs, T + (long)b * 4194304 + h * 512, X + (long)b * 524288, Pb,
                  512, 4096, 512, 8192, (long)b * 8388608 + h * 1024,
                  (t >> 3) * 128, (t & 7) * 128, 0);
}

// L4: softmax, one wave per 1024-chunk of P[b][i][h*1024+j], in place.
__global__ __launch_bounds__(256) void k_softmax_x(unsigned short* __restrict__ S) {
  int g = blockIdx.y * 4 + (threadIdx.x >> 6);
  int b = g >> 10, i = g & 1023;
  long base = (long)b * 8388608 + (long)i * 8192 + (long)blockIdx.x * 1024;
  int lane = threadIdx.x & 63;
  f16x8* p = reinterpret_cast<f16x8*>(S + base);
  f16x8 a = p[lane * 2], bb = p[lane * 2 + 1];
  float v[16];
#pragma unroll
  for (int q = 0; q < 8; ++q) { v[q] = (float)a[q]; v[8 + q] = (float)bb[q]; }
  float m = v[0];
#pragma unroll
  for (int q = 1; q < 16; ++q) m = fmaxf(m, v[q]);
#pragma unroll
  for (int o = 32; o; o >>= 1) m = fmaxf(m, __shfl_xor(m, o));
  float s = 0.f;
#pragma unroll
  for (int q = 0; q < 16; ++q) { v[q] = __expf(v[q] - m); s += v[q]; }
#pragma unroll
  for (int o = 32; o; o >>= 1) s += __shfl_xor(s, o);
  float inv = 1.0f / s;
  f16x8 oa, ob;
#pragma unroll
  for (int q = 0; q < 8; ++q) {
    oa[q] = (_Float16)(v[q] * inv);
    ob[q] = (_Float16)(v[8 + q] * inv);
  }
  p[lane * 2] = oa;
  p[lane * 2 + 1] = ob;
}

// L5+L6 fused: O-partials + last-arriver reduce. grid (8,64).
// The 4 kc-writers of output region (b, y, x) are the blocks with equal
// (b, ih, r) and kc = 0..3; each writes its Opart slab, fences (release:
// buffer_wbl2), bumps cnt[region]. The 4th arriver — whoever it is, no
// co-residency assumption, NO SPINNING (R4 lesson: grid-wide spin barriers
// cost ~ms on MI355X) — acquires (fence invalidates L1/L2 so cross-XCD slabs
// are visible, G16) and sums the 4 slabs into out. Deadlock-free by
// construction; removes the k_reduce launch + gap.
__global__ __launch_bounds__(256, 2) void k_gemm_out(
    const unsigned short* __restrict__ Pb, const unsigned short* __restrict__ VUt,
    float* __restrict__ Opart, float* __restrict__ out, int* __restrict__ cnt) {
  DECL_LDS
  int c = blockIdx.x, w = blockIdx.y;
  int g = c + 8 * (w >> 4);  // 0..31
  int r = w & 15;
  int b = g >> 3, kc = (g >> 1) & 3, ih = g & 1;
  int y = ih * 4 + (r >> 2);  // 0..7  (i-tile)
  int x = r & 3;              // 0..3  (e-tile)
  gemm_core<0, 1>(As, Bs, Pb + (long)b * 8388608 + kc * 2048, VUt + (long)b * 1024,
                  Opart, 2048, 8192, 4096, 512,
                  (long)kc * 2097152 + (long)b * 524288, y * 128, x * 128, kc * 2048);

  __threadfence();  // release: drain stores, write back L2
  __shared__ int lastflag;
  if (threadIdx.x == 0) {
    int region = (b * 8 + y) * 4 + x;  // 128 regions, 4 writers each
    lastflag = (atomicAdd(&cnt[region], 1) == 3);
  }
  __syncthreads();
  if (!lastflag) return;
  __threadfence();  // acquire: invalidate caches; other XCDs' slabs visible

  // reduce this region: 128 rows x 128 cols fp32, float4-ized.
  long base0 = (long)b * 524288 + (long)(y * 128) * 512 + x * 128;
#pragma unroll
  for (int t = 0; t < 16; ++t) {
    int lin = threadIdx.x + t * 256;       // 0..4095
    int rr = lin >> 5, c4 = (lin & 31) * 4;
    long o = base0 + (long)rr * 512 + c4;
    float4 a = *reinterpret_cast<const float4*>(Opart + o);
    float4 bq = *reinterpret_cast<const float4*>(Opart + 2097152 + o);
    float4 cq = *reinterpret_cast<const float4*>(Opart + 4194304 + o);
    float4 dq = *reinterpret_cast<const float4*>(Opart + 6291456 + o);
    float4 ov;
    ov.x = (a.x + bq.x) + (cq.x + dq.x);
    ov.y = (a.y + bq.y) + (cq.y + dq.y);
    ov.z = (a.z + bq.z) + (cq.z + dq.z);
    ov.w = (a.w + bq.w) + (cq.w + dq.w);
    *reinterpret_cast<float4*>(out + o) = ov;
  }
}

__global__ void k_sentinel(float* out, float v) { out[0] = v; }

extern "C" void kernel_launch(void* const* d_in, const int* in_sizes, int n_in,
                              void* d_out, int out_size, void* d_ws, size_t ws_size,
                              hipStream_t stream) {
  // setup_inputs dict order: x, Wk, Wq, Wv, Wu
  const float* x  = (const float*)d_in[0];
  const float* Wk = (const float*)d_in[1];
  const float* Wq = (const float*)d_in[2];
  const float* Wv = (const float*)d_in[3];
  const float* Wu = (const float*)d_in[4];
  float* out = (float*)d_out;

  const long SZ_X = 4096L * 512;
  const size_t NEED = 150994944;  // 144 MiB (we use 140 + counters)

  if (ws_size < NEED) {
    hipMemsetAsync(d_out, 0, (size_t)out_size * 4, stream);
    k_sentinel<<<1, 1, 0, stream>>>(out, (float)ws_size);
    return;
  }

  char* p = (char*)d_ws;
  unsigned short* Xbf  = (unsigned short*)p; p += SZ_X * 2;           //  4 MiB
  unsigned short* Wvut = (unsigned short*)p; p += 8L * 512 * 512 * 2; //  4 MiB [h][e][k]
  unsigned short* Gt   = (unsigned short*)p; p += 8L * 512 * 512 * 2; //  4 MiB [h][b'][a]
  unsigned short* T    = (unsigned short*)p; p += 4096L * 4096 * 2;   // 32 MiB [bt][h*512+b']
  unsigned short* Pb   = (unsigned short*)p; p += 4096L * 8192 * 2;   // 64 MiB [b][i][h*1024+j]
  unsigned short* VUt  = (unsigned short*)p; p += 4096L * 4096 * 2;   // 32 MiB [h*512+e][b*1024+j]
  int* Cnt = (int*)p;                                                  // 512 B (128 regions)
  float* Opart = (float*)T;  // 32 MiB alias: T dead after S-gemm; 4x[4096][512] fp32

  // zero the last-arriver counters (graph-captured; replays each iteration)
  hipMemsetAsync(Cnt, 0, 128 * sizeof(int), stream);

  // L1: x convert + weight folds (fp32-direct staging), one launch
  k_wsetup<<<dim3(8, 288), 256, 0, stream>>>(x, Wq, Wk, Wv, Wu, Xbf, Gt, Wvut);

  // L2: T = X.Gt^T (17.2 GF) + VU^T = Wvut.X^T (17.2 GF), fused
  k_gemm_tv<<<dim3(8, 256), 256, 0, stream>>>(Xbf, Gt, Wvut, T, VUt);

  // L3: P[b][i][h*1024+j] = T.X^T (34.4 GF), B-operand = X (L2-tiny)
  k_gemm_s<<<dim3(8, 256), 256, 0, stream>>>(Xbf, T, Pb);

  // L4: softmax over each 1024-chunk of P, in place
  k_softmax_x<<<dim3(8, 1024), 256, 0, stream>>>(Pb);

  // L5+L6: out partials = P . VU^T, last-arriver blocks reduce into out
  k_gemm_out<<<dim3(8, 64), 256, 0, stream>>>(Pb, VUt, Opart, out, Cnt);
}

// Round 7
// 323.974 us; speedup vs baseline: 3.3822x; 1.0977x over previous
//
#include <hip/hip_runtime.h>
#include <stdint.h>

typedef _Float16 f16x8 __attribute__((ext_vector_type(8)));
typedef float f32x4 __attribute__((ext_vector_type(4)));

__device__ __forceinline__ unsigned short f2h(float f) {
  _Float16 h = (_Float16)f;
  return __builtin_bit_cast(unsigned short, h);
}

#if __has_builtin(__builtin_amdgcn_global_load_lds)
#define HAVE_GLL 1
__device__ __forceinline__ void gload_lds16(const void* g, void* l) {
  auto gp = reinterpret_cast<const __attribute__((address_space(1))) void*>(
      reinterpret_cast<uintptr_t>(g));
  auto lp = reinterpret_cast<__attribute__((address_space(3))) void*>(
      reinterpret_cast<uintptr_t>(l));
  __builtin_amdgcn_global_load_lds(gp, lp, 16, 0, 0);
}
#else
#define HAVE_GLL 0
#endif

// Session ledger (do not retry):
//   R1 8-phase 256^2 port       REGRESSED  (custom derived-waits != m201 template)
//   R2 softmax stats fold       NEUTRAL-   (end-of-kernel VALU burst + L5 restage)
//   R3 launch_bounds (256,4)    NEUTRAL    (132 unified regs already -> 3 waves/SIMD)
//   R4 coop mega-kernel         DISASTER   (grid.sync + fences = ~ms; launch
//                                           boundaries ARE the cheap barrier)
//   R5 last-arriver + fence     DISASTER   (per-block __threadfence = L2
//                                           writeback/inv storm; k_gemm_out 43->160us)
//   R6 fused T->S->softmax      NO DATA    (container failed twice = infra error;
//                                           kernel audited: no hang/OOB/barrier bug)
// R7 = R6 resubmitted verbatim (unchanged A/B vs the R6 prediction).

// ---------------- GEMM core: C[M,N] = A[M,K] * B[N,K]^T (fp16 inputs) ----------------
// 128x128 tile, BK=64, 256 threads (4 waves, 2x2 of 64x64), mfma 16x16x32 f16.
// PROVEN structure, untouched.
template <int OUT, int BVU>
__device__ __forceinline__ void gemm_core(unsigned short* __restrict__ As,
                                          unsigned short* __restrict__ Bs,
                                          const unsigned short* __restrict__ A,
                                          const unsigned short* __restrict__ B,
                                          void* __restrict__ Cv, int K, int lda, int ldb,
                                          int ldc, long coff, int m0, int n0, int kbase) {
  int tid = threadIdx.x;
  int wid = tid >> 6, lane = tid & 63;
  int wm = (wid >> 1) * 64, wn = (wid & 1) * 64;
  int rq = lane >> 4, rl = lane & 15;

  f32x4 acc[4][4];
#pragma unroll
  for (int i = 0; i < 4; ++i)
#pragma unroll
    for (int j = 0; j < 4; ++j) acc[i][j] = (f32x4){0.f, 0.f, 0.f, 0.f};

#if HAVE_GLL
  int cg_ = (lane & 7) ^ ((lane >> 3) & 7);
  int rl8 = lane >> 3;
#endif

  for (int k0 = 0; k0 < K; k0 += 64) {
    long bko;
    if (BVU) {
      int kk = kbase + k0;
      bko = (long)(kk >> 10) * 2097152 + (kk & 1023);
    } else {
      bko = k0;
    }
    __syncthreads();
#if HAVE_GLL
#pragma unroll
    for (int t = 0; t < 4; ++t) {
      int r = wid * 32 + t * 8;
      gload_lds16(&A[(long)(m0 + r + rl8) * lda + k0 + cg_ * 8], &As[r * 64]);
      gload_lds16(&B[(long)(n0 + r + rl8) * ldb + bko + cg_ * 8], &Bs[r * 64]);
    }
#else
#pragma unroll
    for (int it = 0; it < 4; ++it) {
      int idx = tid + it * 256;
      int r = idx >> 3, c = idx & 7;
      int cs = c ^ (r & 7);
      *reinterpret_cast<uint4*>(&As[r * 64 + cs * 8]) =
          *reinterpret_cast<const uint4*>(&A[(long)(m0 + r) * lda + k0 + c * 8]);
      *reinterpret_cast<uint4*>(&Bs[r * 64 + cs * 8]) =
          *reinterpret_cast<const uint4*>(&B[(long)(n0 + r) * ldb + bko + c * 8]);
    }
#endif
    __syncthreads();
#pragma unroll
    for (int ks = 0; ks < 2; ++ks) {
      f16x8 af[4], bfr[4];
      int kc = ks * 4 + rq;
#pragma unroll
      for (int i = 0; i < 4; ++i) {
        int ra = wm + i * 16 + rl;
        af[i] = *reinterpret_cast<const f16x8*>(&As[ra * 64 + ((kc ^ (ra & 7)) << 3)]);
        int rb = wn + i * 16 + rl;
        bfr[i] = *reinterpret_cast<const f16x8*>(&Bs[rb * 64 + ((kc ^ (rb & 7)) << 3)]);
      }
#pragma unroll
      for (int i = 0; i < 4; ++i)
#pragma unroll
        for (int j = 0; j < 4; ++j)
          acc[i][j] = __builtin_amdgcn_mfma_f32_16x16x32_f16(af[i], bfr[j], acc[i][j], 0, 0, 0);
    }
  }

#pragma unroll
  for (int i = 0; i < 4; ++i)
#pragma unroll
    for (int j = 0; j < 4; ++j)
#pragma unroll
      for (int r = 0; r < 4; ++r) {
        int row = m0 + wm + i * 16 + rq * 4 + r;
        int col = n0 + wn + j * 16 + rl;
        float v = acc[i][j][r];
        if (OUT == 1)
          reinterpret_cast<unsigned short*>(Cv)[coff + (long)row * ldc + col] = f2h(v);
        else
          reinterpret_cast<float*>(Cv)[coff + (long)row * ldc + col] = v;
      }
}

// ---------------- w_core: 128x128xBK64 gemm staging from RAW fp32 ----------------
// atrans staging float4-vectorized (R5-validated).
__device__ __forceinline__ void w_core(unsigned short* __restrict__ As,
                                       unsigned short* __restrict__ Bs,
                                       const float* __restrict__ A32,
                                       const float* __restrict__ B32,
                                       unsigned short* __restrict__ C,
                                       int lda, int ldb, bool atrans, int m0, int n0) {
  int tid = threadIdx.x;
  int wid = tid >> 6, lane = tid & 63;
  int wm = (wid >> 1) * 64, wn = (wid & 1) * 64;
  int rq = lane >> 4, rl = lane & 15;

  f32x4 acc[4][4];
#pragma unroll
  for (int i = 0; i < 4; ++i)
#pragma unroll
    for (int j = 0; j < 4; ++j) acc[i][j] = (f32x4){0.f, 0.f, 0.f, 0.f};

  for (int k0 = 0; k0 < 512; k0 += 64) {
    __syncthreads();
    if (!atrans) {
#pragma unroll
      for (int it = 0; it < 8; ++it) {
        int idx = it * 256 + tid;
        int r = idx >> 4, kq = idx & 15;
        float4 v = *reinterpret_cast<const float4*>(&A32[(long)(m0 + r) * lda + k0 + kq * 4]);
        ushort4 u;
        u.x = f2h(v.x); u.y = f2h(v.y); u.z = f2h(v.z); u.w = f2h(v.w);
        int cs = (kq >> 1) ^ (r & 7);
        *reinterpret_cast<ushort4*>(&As[r * 64 + cs * 8 + (kq & 1) * 4]) = u;
      }
    } else {
#pragma unroll
      for (int it = 0; it < 8; ++it) {
        int idx = it * 256 + tid;
        int d = idx >> 5, mq = (idx & 31) << 2;
        float4 v = *reinterpret_cast<const float4*>(&A32[(long)(k0 + d) * 512 + m0 + mq]);
        float vv[4] = {v.x, v.y, v.z, v.w};
#pragma unroll
        for (int q = 0; q < 4; ++q) {
          int m = mq + q;
          int cs = (d >> 3) ^ (m & 7);
          As[m * 64 + cs * 8 + (d & 7)] = f2h(vv[q]);
        }
      }
    }
#pragma unroll
    for (int it = 0; it < 8; ++it) {
      int idx = it * 256 + tid;
      int r = idx >> 4, kq = idx & 15;
      float4 v = *reinterpret_cast<const float4*>(&B32[(long)(n0 + r) * ldb + k0 + kq * 4]);
      ushort4 u;
      u.x = f2h(v.x); u.y = f2h(v.y); u.z = f2h(v.z); u.w = f2h(v.w);
      int cs = (kq >> 1) ^ (r & 7);
      *reinterpret_cast<ushort4*>(&Bs[r * 64 + cs * 8 + (kq & 1) * 4]) = u;
    }
    __syncthreads();
#pragma unroll
    for (int ks = 0; ks < 2; ++ks) {
      f16x8 af[4], bfr[4];
      int kc = ks * 4 + rq;
#pragma unroll
      for (int i = 0; i < 4; ++i) {
        int ra = wm + i * 16 + rl;
        af[i] = *reinterpret_cast<const f16x8*>(&As[ra * 64 + ((kc ^ (ra & 7)) << 3)]);
        int rb = wn + i * 16 + rl;
        bfr[i] = *reinterpret_cast<const f16x8*>(&Bs[rb * 64 + ((kc ^ (rb & 7)) << 3)]);
      }
#pragma unroll
      for (int i = 0; i < 4; ++i)
#pragma unroll
        for (int j = 0; j < 4; ++j)
          acc[i][j] = __builtin_amdgcn_mfma_f32_16x16x32_f16(af[i], bfr[j], acc[i][j], 0, 0, 0);
    }
  }

#pragma unroll
  for (int i = 0; i < 4; ++i)
#pragma unroll
    for (int j = 0; j < 4; ++j)
#pragma unroll
      for (int r = 0; r < 4; ++r) {
        int row = m0 + wm + i * 16 + rq * 4 + r;
        int col = n0 + wn + j * 16 + rl;
        C[(long)row * 512 + col] = f2h(acc[i][j][r]);
      }
}

#define DECL_LDS \
  __shared__ unsigned short As[128 * 64]; \
  __shared__ unsigned short Bs[128 * 64];

// L1: x convert + weight folds. grid (8,288).
__global__ __launch_bounds__(256, 2) void k_wsetup(
    const float* __restrict__ x, const float* __restrict__ Wq, const float* __restrict__ Wk,
    const float* __restrict__ Wv, const float* __restrict__ Wu,
    unsigned short* __restrict__ Xh, unsigned short* __restrict__ Gt,
    unsigned short* __restrict__ Wvut) {
  DECL_LDS
  int c = blockIdx.x, w = blockIdx.y;
  if (w >= 32) {
    int i = ((w - 32) * 8 + c) * 256 + threadIdx.x;
    float4 v = reinterpret_cast<const float4*>(x)[i];
    ushort4 u;
    u.x = f2h(v.x); u.y = f2h(v.y); u.z = f2h(v.z); u.w = f2h(v.w);
    reinterpret_cast<ushort4*>(Xh)[i] = u;
    return;
  }
  const float *A32, *B32;
  unsigned short* C;
  int lda;
  bool atrans;
  int t;
  if (w < 16) {
    A32 = Wq + c * 512; B32 = Wk + c * 512; C = Gt + (long)c * 262144;
    lda = 4096; atrans = false; t = w;
  } else {
    A32 = Wu + (long)c * 262144; B32 = Wv + c * 512; C = Wvut + (long)c * 262144;
    lda = 512; atrans = true; t = w - 16;
  }
  w_core(As, Bs, A32, B32, C, lda, 4096, atrans, (t >> 2) * 128, (t & 3) * 128);
}

// L2: VU projection only (T-leg moved into k_fused_s). grid (8,128).
__global__ __launch_bounds__(256, 2) void k_gemm_vu(
    const unsigned short* __restrict__ X, const unsigned short* __restrict__ Wvut,
    unsigned short* __restrict__ VUt) {
  DECL_LDS
  int c = blockIdx.x, wp = blockIdx.y;
  gemm_core<1, 0>(As, Bs, Wvut, X, VUt, 512, 512, 512, 4096, 0,
                  (4 * c + (wp & 3)) * 128, (wp >> 2) * 128, 0);
}

// L3: fused T->S->softmax. grid (8 h, 128 (b,i32)) = 1024 blocks, 256 thr.
// Per block: 32-row strip of one (b,h):
//   A: Tl[32][512] = X[strip] . Gt_h^T  (LDS only; T never in HBM)
//   B: 8 j-tiles: S[32][128] = Tl . X_b[jtile]^T -> raw fp16 to Pb; row-max only
//   C: one exp pass over own L2-hot strip: exp(v-m), 1/sum scale, write back
// LDS 52 KiB -> 3 blocks/CU. Plain __syncthreads only (no fences/custom waits).
__global__ __launch_bounds__(256, 3) void k_fused_s(
    const unsigned short* __restrict__ X, const unsigned short* __restrict__ Gt,
    unsigned short* __restrict__ Pb) {
  __shared__ unsigned short Lds[26624];  // 53248 B: As(4K) | Bs(16K) | Tl(32K)
  unsigned short* As = Lds;              // [32][64] staging, phase A only
  unsigned short* Bs = Lds + 2048;       // [128][64] staging
  unsigned short* Tl = Lds + 10240;      // [8 chunks][32 rows][64 k], XOR-swizzled
  float* smaxL = reinterpret_cast<float*>(Lds);       // aliases As (dead in B/C)
  float* mfin = reinterpret_cast<float*>(Lds) + 64;   // [32] final row max

  const int h = blockIdx.x, w = blockIdx.y;
  const int b = w >> 5, i0 = (w & 31) * 32;
  const long g0 = (long)b * 1024 + i0;  // global X row of strip start
  const unsigned short* Gh = Gt + (long)h * 262144;

  const int tid = threadIdx.x, wid = tid >> 6, lane = tid & 63;
  const int wm2 = (wid >> 1) * 16, wn2 = (wid & 1) * 64;  // wave tile 16 x 64
  const int rq = lane >> 4, rl = lane & 15;
  const int ra = wm2 + rl;  // A-frag row (fixed per lane)
#if HAVE_GLL
  const int cg = (lane & 7) ^ ((lane >> 3) & 7);
  const int rl8 = lane >> 3;
#endif

  // ---------------- phase A: Tl = X[strip] . Gh^T ----------------
  for (int n0 = 0; n0 < 512; n0 += 128) {
    f32x4 acc[4];
#pragma unroll
    for (int jn = 0; jn < 4; ++jn) acc[jn] = (f32x4){0.f, 0.f, 0.f, 0.f};
    for (int k0 = 0; k0 < 512; k0 += 64) {
      __syncthreads();
#if HAVE_GLL
      gload_lds16(&X[(g0 + wid * 8 + rl8) * 512 + k0 + cg * 8], &As[(wid * 8) * 64]);
#pragma unroll
      for (int t = 0; t < 4; ++t) {
        int r = wid * 32 + t * 8;
        gload_lds16(&Gh[(long)(n0 + r + rl8) * 512 + k0 + cg * 8], &Bs[r * 64]);
      }
#else
      {
        int r = tid >> 3, c = tid & 7;  // 256 thr = 32 rows x 8 chunks
        int cs = c ^ (r & 7);
        *reinterpret_cast<uint4*>(&As[r * 64 + cs * 8]) =
            *reinterpret_cast<const uint4*>(&X[(g0 + r) * 512 + k0 + c * 8]);
      }
#pragma unroll
      for (int it = 0; it < 4; ++it) {
        int idx = tid + it * 256;
        int r = idx >> 3, c = idx & 7;
        int cs = c ^ (r & 7);
        *reinterpret_cast<uint4*>(&Bs[r * 64 + cs * 8]) =
            *reinterpret_cast<const uint4*>(&Gh[(long)(n0 + r) * 512 + k0 + c * 8]);
      }
#endif
      __syncthreads();
#pragma unroll
      for (int ks = 0; ks < 2; ++ks) {
        int kc = ks * 4 + rq;
        f16x8 af = *reinterpret_cast<const f16x8*>(&As[ra * 64 + ((kc ^ (ra & 7)) << 3)]);
#pragma unroll
        for (int jn = 0; jn < 4; ++jn) {
          int rb = wn2 + jn * 16 + rl;
          f16x8 bf = *reinterpret_cast<const f16x8*>(&Bs[rb * 64 + ((kc ^ (rb & 7)) << 3)]);
          acc[jn] = __builtin_amdgcn_mfma_f32_16x16x32_f16(af, bf, acc[jn], 0, 0, 0);
        }
      }
    }
    // epilogue: acc -> Tl (fp16, swizzled). row = wm2+rq*4+r; n = n0+wn2+jn*16+rl.
    // n maps to (chunk = n>>6, slot q = (n>>3)&7, e = n&7).
#pragma unroll
    for (int jn = 0; jn < 4; ++jn)
#pragma unroll
      for (int r = 0; r < 4; ++r) {
        int row = wm2 + rq * 4 + r;
        int n = n0 + wn2 + jn * 16 + rl;
        Tl[(n >> 6) * 2048 + row * 64 + ((((n >> 3) & 7) ^ (row & 7)) << 3) + (n & 7)] =
            f2h(acc[jn][r]);
      }
  }

  // ---------------- phase B: S j-tiles, raw store + row-max ----------------
  float rmax[4] = {-3.4e38f, -3.4e38f, -3.4e38f, -3.4e38f};
  const unsigned short* Xb = X + (long)b * 524288;  // X_b rows
  for (int j0 = 0; j0 < 1024; j0 += 128) {
    f32x4 acc[4];
#pragma unroll
    for (int jn = 0; jn < 4; ++jn) acc[jn] = (f32x4){0.f, 0.f, 0.f, 0.f};
    for (int k0 = 0; k0 < 512; k0 += 64) {
      __syncthreads();
#if HAVE_GLL
#pragma unroll
      for (int t = 0; t < 4; ++t) {
        int r = wid * 32 + t * 8;
        gload_lds16(&Xb[(long)(j0 + r + rl8) * 512 + k0 + cg * 8], &Bs[r * 64]);
      }
#else
#pragma unroll
      for (int it = 0; it < 4; ++it) {
        int idx = tid + it * 256;
        int r = idx >> 3, c = idx & 7;
        int cs = c ^ (r & 7);
        *reinterpret_cast<uint4*>(&Bs[r * 64 + cs * 8]) =
            *reinterpret_cast<const uint4*>(&Xb[(long)(j0 + r) * 512 + k0 + c * 8]);
      }
#endif
      __syncthreads();
#pragma unroll
      for (int ks = 0; ks < 2; ++ks) {
        int kc = ks * 4 + rq;
        f16x8 af = *reinterpret_cast<const f16x8*>(
            &Tl[(k0 >> 6) * 2048 + ra * 64 + ((kc ^ (ra & 7)) << 3)]);
#pragma unroll
        for (int jn = 0; jn < 4; ++jn) {
          int rb = wn2 + jn * 16 + rl;
          f16x8 bf = *reinterpret_cast<const f16x8*>(&Bs[rb * 64 + ((kc ^ (rb & 7)) << 3)]);
          acc[jn] = __builtin_amdgcn_mfma_f32_16x16x32_f16(af, bf, acc[jn], 0, 0, 0);
        }
      }
    }
    // raw S store + per-row tile max (no exp here — R2 lesson)
#pragma unroll
    for (int r = 0; r < 4; ++r) {
      int row = wm2 + rq * 4 + r;
      float m4 = fmaxf(fmaxf(acc[0][r], acc[1][r]), fmaxf(acc[2][r], acc[3][r]));
#pragma unroll
      for (int o = 1; o < 16; o <<= 1) m4 = fmaxf(m4, __shfl_xor(m4, o));
      rmax[r] = fmaxf(rmax[r], m4);
#pragma unroll
      for (int jn = 0; jn < 4; ++jn) {
        int col = j0 + wn2 + jn * 16 + rl;
        Pb[(g0 + row) * 8192 + h * 1024 + col] = f2h(acc[jn][r]);
      }
    }
  }
  // combine row-max across the 2 column-wave halves (As region is dead now)
  __syncthreads();  // all waves done with Bs/Tl reads & raw stores issued
  if (rl == 0) {
#pragma unroll
    for (int r = 0; r < 4; ++r) smaxL[wid * 16 + rq * 4 + r] = rmax[r];
  }
  __syncthreads();
  if (tid < 32) {
    int row = tid;
    mfin[row] = (row < 16) ? fmaxf(smaxL[row], smaxL[16 + row])
                           : fmaxf(smaxL[16 + row], smaxL[32 + row]);
  }
  __syncthreads();

  // ---------------- phase C: exp + normalize own strip (L2-hot) ----------------
  {
    int row = wid * 8 + (lane >> 3);  // 4 waves x 8 rows
    int cgp = lane & 7;               // 8 col-groups x 128
    float m = mfin[row];
    f16x8* pp = reinterpret_cast<f16x8*>(
        const_cast<unsigned short*>(Pb) + (g0 + row) * 8192 + h * 1024 + cgp * 128);
    f16x8 ex[16];
    float s = 0.f;
#pragma unroll
    for (int q = 0; q < 16; ++q) {
      f16x8 v = pp[q];
      f16x8 e;
#pragma unroll
      for (int t = 0; t < 8; ++t) {
        float f = __expf((float)v[t] - m);
        s += f;
        e[t] = (_Float16)f;
      }
      ex[q] = e;
    }
#pragma unroll
    for (int o = 1; o < 8; o <<= 1) s += __shfl_xor(s, o);
    float inv = 1.0f / s;
#pragma unroll
    for (int q = 0; q < 16; ++q) {
      f16x8 e = ex[q];
      f16x8 ov;
#pragma unroll
      for (int t = 0; t < 8; ++t) ov[t] = (_Float16)((float)e[t] * inv);
      pp[q] = ov;
    }
  }
}

// L5: O-partials. grid (8,64). R0 form (no fences, no counters).
__global__ __launch_bounds__(256, 2) void k_gemm_out(
    const unsigned short* __restrict__ Pb, const unsigned short* __restrict__ VUt,
    float* __restrict__ Opart) {
  DECL_LDS
  int c = blockIdx.x, w = blockIdx.y;
  int g = c + 8 * (w >> 4);
  int r = w & 15;
  int b = g >> 3, kc = (g >> 1) & 3, ih = g & 1;
  int y = ih * 4 + (r >> 2);
  int x = r & 3;
  gemm_core<0, 1>(As, Bs, Pb + (long)b * 8388608 + kc * 2048, VUt + (long)b * 1024,
                  Opart, 2048, 8192, 4096, 512,
                  (long)kc * 2097152 + (long)b * 524288, y * 128, x * 128, kc * 2048);
}

// L6: out = sum of 4 partials. R0 form.
__global__ __launch_bounds__(256) void k_reduce(const float* __restrict__ Opart,
                                                float* __restrict__ out) {
  int i = blockIdx.x * 256 + threadIdx.x;
  float4 a = reinterpret_cast<const float4*>(Opart)[i];
  float4 b = reinterpret_cast<const float4*>(Opart + 2097152)[i];
  float4 c = reinterpret_cast<const float4*>(Opart + 4194304)[i];
  float4 d = reinterpret_cast<const float4*>(Opart + 6291456)[i];
  float4 o;
  o.x = (a.x + b.x) + (c.x + d.x);
  o.y = (a.y + b.y) + (c.y + d.y);
  o.z = (a.z + b.z) + (c.z + d.z);
  o.w = (a.w + b.w) + (c.w + d.w);
  reinterpret_cast<float4*>(out)[i] = o;
}

__global__ void k_sentinel(float* out, float v) { out[0] = v; }

extern "C" void kernel_launch(void* const* d_in, const int* in_sizes, int n_in,
                              void* d_out, int out_size, void* d_ws, size_t ws_size,
                              hipStream_t stream) {
  // setup_inputs dict order: x, Wk, Wq, Wv, Wu
  const float* x  = (const float*)d_in[0];
  const float* Wk = (const float*)d_in[1];
  const float* Wq = (const float*)d_in[2];
  const float* Wv = (const float*)d_in[3];
  const float* Wu = (const float*)d_in[4];
  float* out = (float*)d_out;

  const long SZ_X = 4096L * 512;
  const size_t NEED = 150994944;  // 144 MiB

  if (ws_size < NEED) {
    hipMemsetAsync(d_out, 0, (size_t)out_size * 4, stream);
    k_sentinel<<<1, 1, 0, stream>>>(out, (float)ws_size);
    return;
  }

  char* p = (char*)d_ws;
  unsigned short* Xbf  = (unsigned short*)p; p += SZ_X * 2;           //  4 MiB
  unsigned short* Wvut = (unsigned short*)p; p += 8L * 512 * 512 * 2; //  4 MiB [h][e][k]
  unsigned short* Gt   = (unsigned short*)p; p += 8L * 512 * 512 * 2; //  4 MiB [h][b'][a]
  unsigned short* T    = (unsigned short*)p; p += 4096L * 4096 * 2;   // 32 MiB (Opart home)
  unsigned short* Pb   = (unsigned short*)p; p += 4096L * 8192 * 2;   // 64 MiB [b][i][h*1024+j]
  unsigned short* VUt  = (unsigned short*)p;                          // 32 MiB [h*512+e][b*1024+j]
  float* Opart = (float*)T;  // 4 x [4096][512] fp32

  // L1: x convert + weight folds
  k_wsetup<<<dim3(8, 288), 256, 0, stream>>>(x, Wq, Wk, Wv, Wu, Xbf, Gt, Wvut);

  // L2: VU^T = Wvut.X^T (17.2 GF)
  k_gemm_vu<<<dim3(8, 128), 256, 0, stream>>>(Xbf, Wvut, VUt);

  // L3: fused T->S->softmax (51.6 GF); T and raw-softmax pass never hit HBM
  k_fused_s<<<dim3(8, 128), 256, 0, stream>>>(Xbf, Gt, Pb);

  // L5: out partials = P . VU^T
  k_gemm_out<<<dim3(8, 64), 256, 0, stream>>>(Pb, VUt, Opart);

  // L6: out = sum of 4 partials
  k_reduce<<<2048, 256, 0, stream>>>(Opart, out);
}

// Round 8
// 255.076 us; speedup vs baseline: 4.2958x; 1.2701x over previous
//
#include <hip/hip_runtime.h>
#include <stdint.h>

typedef _Float16 f16x8 __attribute__((ext_vector_type(8)));
typedef float f32x4 __attribute__((ext_vector_type(4)));

__device__ __forceinline__ unsigned short f2h(float f) {
  _Float16 h = (_Float16)f;
  return __builtin_bit_cast(unsigned short, h);
}

#if __has_builtin(__builtin_amdgcn_global_load_lds)
#define HAVE_GLL 1
__device__ __forceinline__ void gload_lds16(const void* g, void* l) {
  auto gp = reinterpret_cast<const __attribute__((address_space(1))) void*>(
      reinterpret_cast<uintptr_t>(g));
  auto lp = reinterpret_cast<__attribute__((address_space(3))) void*>(
      reinterpret_cast<uintptr_t>(l));
  __builtin_amdgcn_global_load_lds(gp, lp, 16, 0, 0);
}
#else
#define HAVE_GLL 0
#endif

// ============================ FINAL (R8) ============================
// Best-known configuration: the proven 6-launch pipeline (R0) + w_core atrans
// float4 staging (validated R5-R7). Session ledger — all deviations lost:
//   R1 8-phase 256^2 port       REGRESSED  (custom derived-waits != m201 template;
//                                           do not re-derive sync structures)
//   R2 softmax stats fold       NEUTRAL-   (end-of-kernel VALU burst + L5 restage
//                                           repurchased the saved softmax pass)
//   R3 launch_bounds (256,4)    NEUTRAL    (64 VGPR + ~68 AGPR = 132 unified regs
//                                           -> already 3 waves/SIMD; no lever)
//   R4 coop mega-kernel         DISASTER   (grid.sync + fences ~ms; launch
//                                           boundaries ARE the cheap barrier)
//   R5 last-arriver + fence     DISASTER   (per-block __threadfence = L2
//                                           writeback/inv storm; 43->160us)
//   R6/R7 strip-fused T->S->SM  REGRESSED  (M=32 strip: 4x worse B-staging
//                                           amortization; "L2-hot" phase-C
//                                           rewrite actually hit HBM: 125MB W)
// Structural floor of this decomposition: per-GEMM at the plain-HIP 2-barrier
// ceiling (MfmaUtil ~30%), ~60us inter-launch residual with no safe removal
// mechanism on MI355X.

// ---------------- GEMM core: C[M,N] = A[M,K] * B[N,K]^T (fp16 inputs) ----------------
// 128x128 tile, BK=64, 256 threads (4 waves, 2x2 of 64x64), mfma 16x16x32 f16.
// LDS XOR-swizzled at 16B granularity; staging via global_load_lds(16B).
// OUT: 0 fp32 store, 1 fp16 store. BVU: B rows live in VUt[h*512+e][b*1024+j].
template <int OUT, int BVU>
__device__ __forceinline__ void gemm_core(unsigned short* __restrict__ As,
                                          unsigned short* __restrict__ Bs,
                                          const unsigned short* __restrict__ A,
                                          const unsigned short* __restrict__ B,
                                          void* __restrict__ Cv, int K, int lda, int ldb,
                                          int ldc, long coff, int m0, int n0, int kbase) {
  int tid = threadIdx.x;
  int wid = tid >> 6, lane = tid & 63;
  int wm = (wid >> 1) * 64, wn = (wid & 1) * 64;
  int rq = lane >> 4, rl = lane & 15;

  f32x4 acc[4][4];
#pragma unroll
  for (int i = 0; i < 4; ++i)
#pragma unroll
    for (int j = 0; j < 4; ++j) acc[i][j] = (f32x4){0.f, 0.f, 0.f, 0.f};

#if HAVE_GLL
  int cg_ = (lane & 7) ^ ((lane >> 3) & 7);  // permuted global chunk -> swizzled LDS
  int rl8 = lane >> 3;                       // row within 8-row group
#endif

  for (int k0 = 0; k0 < K; k0 += 64) {
    long bko;
    if (BVU) {
      int kk = kbase + k0;
      bko = (long)(kk >> 10) * 2097152 + (kk & 1023);
    } else {
      bko = k0;
    }
    __syncthreads();
#if HAVE_GLL
#pragma unroll
    for (int t = 0; t < 4; ++t) {
      int r = wid * 32 + t * 8;  // uniform slab base row
      gload_lds16(&A[(long)(m0 + r + rl8) * lda + k0 + cg_ * 8], &As[r * 64]);
      gload_lds16(&B[(long)(n0 + r + rl8) * ldb + bko + cg_ * 8], &Bs[r * 64]);
    }
#else
#pragma unroll
    for (int it = 0; it < 4; ++it) {
      int idx = tid + it * 256;
      int r = idx >> 3, c = idx & 7;
      int cs = c ^ (r & 7);
      *reinterpret_cast<uint4*>(&As[r * 64 + cs * 8]) =
          *reinterpret_cast<const uint4*>(&A[(long)(m0 + r) * lda + k0 + c * 8]);
      *reinterpret_cast<uint4*>(&Bs[r * 64 + cs * 8]) =
          *reinterpret_cast<const uint4*>(&B[(long)(n0 + r) * ldb + bko + c * 8]);
    }
#endif
    __syncthreads();
#pragma unroll
    for (int ks = 0; ks < 2; ++ks) {
      f16x8 af[4], bfr[4];
      int kc = ks * 4 + rq;
#pragma unroll
      for (int i = 0; i < 4; ++i) {
        int ra = wm + i * 16 + rl;
        af[i] = *reinterpret_cast<const f16x8*>(&As[ra * 64 + ((kc ^ (ra & 7)) << 3)]);
        int rb = wn + i * 16 + rl;
        bfr[i] = *reinterpret_cast<const f16x8*>(&Bs[rb * 64 + ((kc ^ (rb & 7)) << 3)]);
      }
#pragma unroll
      for (int i = 0; i < 4; ++i)
#pragma unroll
        for (int j = 0; j < 4; ++j)
          acc[i][j] = __builtin_amdgcn_mfma_f32_16x16x32_f16(af[i], bfr[j], acc[i][j], 0, 0, 0);
    }
  }

#pragma unroll
  for (int i = 0; i < 4; ++i)
#pragma unroll
    for (int j = 0; j < 4; ++j)
#pragma unroll
      for (int r = 0; r < 4; ++r) {
        int row = m0 + wm + i * 16 + rq * 4 + r;
        int col = n0 + wn + j * 16 + rl;
        float v = acc[i][j][r];
        if (OUT == 1)
          reinterpret_cast<unsigned short*>(Cv)[coff + (long)row * ldc + col] = f2h(v);
        else
          reinterpret_cast<float*>(Cv)[coff + (long)row * ldc + col] = v;
      }
}

// ---------------- w_core: same 128x128xBK64 gemm but staging from RAW fp32 ----------------
// atrans staging float4-vectorized (R5-validated; contiguous along m).
__device__ __forceinline__ void w_core(unsigned short* __restrict__ As,
                                       unsigned short* __restrict__ Bs,
                                       const float* __restrict__ A32,
                                       const float* __restrict__ B32,
                                       unsigned short* __restrict__ C,
                                       int lda, int ldb, bool atrans, int m0, int n0) {
  int tid = threadIdx.x;
  int wid = tid >> 6, lane = tid & 63;
  int wm = (wid >> 1) * 64, wn = (wid & 1) * 64;
  int rq = lane >> 4, rl = lane & 15;

  f32x4 acc[4][4];
#pragma unroll
  for (int i = 0; i < 4; ++i)
#pragma unroll
    for (int j = 0; j < 4; ++j) acc[i][j] = (f32x4){0.f, 0.f, 0.f, 0.f};

  for (int k0 = 0; k0 < 512; k0 += 64) {
    __syncthreads();
    if (!atrans) {
#pragma unroll
      for (int it = 0; it < 8; ++it) {
        int idx = it * 256 + tid;
        int r = idx >> 4, kq = idx & 15;
        float4 v = *reinterpret_cast<const float4*>(&A32[(long)(m0 + r) * lda + k0 + kq * 4]);
        ushort4 u;
        u.x = f2h(v.x); u.y = f2h(v.y); u.z = f2h(v.z); u.w = f2h(v.w);
        int cs = (kq >> 1) ^ (r & 7);
        *reinterpret_cast<ushort4*>(&As[r * 64 + cs * 8 + (kq & 1) * 4]) = u;
      }
    } else {
#pragma unroll
      for (int it = 0; it < 8; ++it) {
        int idx = it * 256 + tid;
        int d = idx >> 5, mq = (idx & 31) << 2;
        float4 v = *reinterpret_cast<const float4*>(&A32[(long)(k0 + d) * 512 + m0 + mq]);
        float vv[4] = {v.x, v.y, v.z, v.w};
#pragma unroll
        for (int q = 0; q < 4; ++q) {
          int m = mq + q;
          int cs = (d >> 3) ^ (m & 7);
          As[m * 64 + cs * 8 + (d & 7)] = f2h(vv[q]);
        }
      }
    }
#pragma unroll
    for (int it = 0; it < 8; ++it) {
      int idx = it * 256 + tid;
      int r = idx >> 4, kq = idx & 15;
      float4 v = *reinterpret_cast<const float4*>(&B32[(long)(n0 + r) * ldb + k0 + kq * 4]);
      ushort4 u;
      u.x = f2h(v.x); u.y = f2h(v.y); u.z = f2h(v.z); u.w = f2h(v.w);
      int cs = (kq >> 1) ^ (r & 7);
      *reinterpret_cast<ushort4*>(&Bs[r * 64 + cs * 8 + (kq & 1) * 4]) = u;
    }
    __syncthreads();
#pragma unroll
    for (int ks = 0; ks < 2; ++ks) {
      f16x8 af[4], bfr[4];
      int kc = ks * 4 + rq;
#pragma unroll
      for (int i = 0; i < 4; ++i) {
        int ra = wm + i * 16 + rl;
        af[i] = *reinterpret_cast<const f16x8*>(&As[ra * 64 + ((kc ^ (ra & 7)) << 3)]);
        int rb = wn + i * 16 + rl;
        bfr[i] = *reinterpret_cast<const f16x8*>(&Bs[rb * 64 + ((kc ^ (rb & 7)) << 3)]);
      }
#pragma unroll
      for (int i = 0; i < 4; ++i)
#pragma unroll
        for (int j = 0; j < 4; ++j)
          acc[i][j] = __builtin_amdgcn_mfma_f32_16x16x32_f16(af[i], bfr[j], acc[i][j], 0, 0, 0);
    }
  }

#pragma unroll
  for (int i = 0; i < 4; ++i)
#pragma unroll
    for (int j = 0; j < 4; ++j)
#pragma unroll
      for (int r = 0; r < 4; ++r) {
        int row = m0 + wm + i * 16 + rq * 4 + r;
        int col = n0 + wn + j * 16 + rl;
        C[(long)row * 512 + col] = f2h(acc[i][j][r]);
      }
}

#define DECL_LDS \
  __shared__ unsigned short As[128 * 64]; \
  __shared__ unsigned short Bs[128 * 64];

// L1 (setup+folds merged): grid (8, 288).
// w>=32: convert x fp32->fp16; w<16: Gt fold; w in [16,32): Wvut fold (atrans).
__global__ __launch_bounds__(256, 2) void k_wsetup(
    const float* __restrict__ x, const float* __restrict__ Wq, const float* __restrict__ Wk,
    const float* __restrict__ Wv, const float* __restrict__ Wu,
    unsigned short* __restrict__ Xh, unsigned short* __restrict__ Gt,
    unsigned short* __restrict__ Wvut) {
  DECL_LDS
  int c = blockIdx.x, w = blockIdx.y;
  if (w >= 32) {
    int i = ((w - 32) * 8 + c) * 256 + threadIdx.x;
    float4 v = reinterpret_cast<const float4*>(x)[i];
    ushort4 u;
    u.x = f2h(v.x); u.y = f2h(v.y); u.z = f2h(v.z); u.w = f2h(v.w);
    reinterpret_cast<ushort4*>(Xh)[i] = u;
    return;
  }
  const float *A32, *B32;
  unsigned short* C;
  int lda;
  bool atrans;
  int t;
  if (w < 16) {
    A32 = Wq + c * 512; B32 = Wk + c * 512; C = Gt + (long)c * 262144;
    lda = 4096; atrans = false; t = w;
  } else {
    A32 = Wu + (long)c * 262144; B32 = Wv + c * 512; C = Wvut + (long)c * 262144;
    lda = 512; atrans = true; t = w - 16;
  }
  w_core(As, Bs, A32, B32, C, lda, 4096, atrans, (t >> 2) * 128, (t & 3) * 128);
}

// L2: T + VU projections fused, grid (8,256). ONE gemm_core<1,0> call.
// w<128 : T[bt][h*512+b'] = sum_a X[bt,a] * Gt_h[b',a]; h = c (XCD-pinned).
// w>=128: VUt[h*512+e][b*1024+j] = sum_k Wvut_h[e,k] * X[b*1024+j,k].
__global__ __launch_bounds__(256, 2) void k_gemm_tv(
    const unsigned short* __restrict__ X, const unsigned short* __restrict__ Gt,
    const unsigned short* __restrict__ Wvut, unsigned short* __restrict__ T,
    unsigned short* __restrict__ VUt) {
  DECL_LDS
  int c = blockIdx.x, w = blockIdx.y;
  const unsigned short *A, *B;
  unsigned short* C;
  long coff;
  int m0, n0;
  if (w < 128) {
    A = X; B = Gt + (long)c * 262144; C = T;
    coff = (long)c * 512; m0 = (w >> 2) * 128; n0 = (w & 3) * 128;
  } else {
    int wp = w - 128;
    A = Wvut; B = X; C = VUt;
    coff = 0; m0 = (4 * c + (wp & 3)) * 128; n0 = (wp >> 2) * 128;
  }
  gemm_core<1, 0>(As, Bs, A, B, C, 512, 512, 512, 4096, coff, m0, n0, 0);
}

// L3: S-gemm, grid (8,256). z = c + 8*(w>>6) -> (b,h) pinned to XCD h.
// P[b][i][h*1024+j] = sum_b' T[b*1024+i, h*512+b'] * X[b*1024+j, b'].
__global__ __launch_bounds__(256, 2) void k_gemm_s(
    const unsigned short* __restrict__ X, const unsigned short* __restrict__ T,
    unsigned short* __restrict__ Pb) {
  DECL_LDS
  int c = blockIdx.x, w = blockIdx.y;
  int z = c + 8 * (w >> 6), t = w & 63;
  int b = z >> 3, h = z & 7;
  gemm_core<1, 0>(As, Bs, T + (long)b * 4194304 + h * 512, X + (long)b * 524288, Pb,
                  512, 4096, 512, 8192, (long)b * 8388608 + h * 1024,
                  (t >> 3) * 128, (t & 7) * 128, 0);
}

// L4: softmax, one wave per 1024-chunk of P[b][i][h*1024+j], in place.
// grid (8,1024): h = blockIdx.x (XCD-aligned with the S-gemm writer).
__global__ __launch_bounds__(256) void k_softmax_x(unsigned short* __restrict__ S) {
  int g = blockIdx.y * 4 + (threadIdx.x >> 6);
  int b = g >> 10, i = g & 1023;
  long base = (long)b * 8388608 + (long)i * 8192 + (long)blockIdx.x * 1024;
  int lane = threadIdx.x & 63;
  f16x8* p = reinterpret_cast<f16x8*>(S + base);
  f16x8 a = p[lane * 2], bb = p[lane * 2 + 1];
  float v[16];
#pragma unroll
  for (int q = 0; q < 8; ++q) { v[q] = (float)a[q]; v[8 + q] = (float)bb[q]; }
  float m = v[0];
#pragma unroll
  for (int q = 1; q < 16; ++q) m = fmaxf(m, v[q]);
#pragma unroll
  for (int o = 32; o; o >>= 1) m = fmaxf(m, __shfl_xor(m, o));
  float s = 0.f;
#pragma unroll
  for (int q = 0; q < 16; ++q) { v[q] = __expf(v[q] - m); s += v[q]; }
#pragma unroll
  for (int o = 32; o; o >>= 1) s += __shfl_xor(s, o);
  float inv = 1.0f / s;
  f16x8 oa, ob;
#pragma unroll
  for (int q = 0; q < 8; ++q) {
    oa[q] = (_Float16)(v[q] * inv);
    ob[q] = (_Float16)(v[8 + q] * inv);
  }
  p[lane * 2] = oa;
  p[lane * 2 + 1] = ob;
}

// L5: O-partials: Opart[kc][b*1024+i][e] = sum_{kk in chunk} Pb[b][i][kk] *
// VUt[(kk>>10)*512+e][b*1024+(kk&1023)]. grid (8,64), plain fp32 stores.
__global__ __launch_bounds__(256, 2) void k_gemm_out(
    const unsigned short* __restrict__ Pb, const unsigned short* __restrict__ VUt,
    float* __restrict__ Opart) {
  DECL_LDS
  int c = blockIdx.x, w = blockIdx.y;
  int g = c + 8 * (w >> 4);  // 0..31
  int r = w & 15;
  int b = g >> 3, kc = (g >> 1) & 3, ih = g & 1;
  int y = ih * 4 + (r >> 2);  // 0..7  (i-tile)
  int x = r & 3;              // 0..3  (e-tile)
  gemm_core<0, 1>(As, Bs, Pb + (long)b * 8388608 + kc * 2048, VUt + (long)b * 1024,
                  Opart, 2048, 8192, 4096, 512,
                  (long)kc * 2097152 + (long)b * 524288, y * 128, x * 128, kc * 2048);
}

// L6: out[i] = sum_kc Opart[kc][i]. 2M floats, float4 per thread.
__global__ __launch_bounds__(256) void k_reduce(const float* __restrict__ Opart,
                                                float* __restrict__ out) {
  int i = blockIdx.x * 256 + threadIdx.x;
  float4 a = reinterpret_cast<const float4*>(Opart)[i];
  float4 b = reinterpret_cast<const float4*>(Opart + 2097152)[i];
  float4 c = reinterpret_cast<const float4*>(Opart + 4194304)[i];
  float4 d = reinterpret_cast<const float4*>(Opart + 6291456)[i];
  float4 o;
  o.x = (a.x + b.x) + (c.x + d.x);
  o.y = (a.y + b.y) + (c.y + d.y);
  o.z = (a.z + b.z) + (c.z + d.z);
  o.w = (a.w + b.w) + (c.w + d.w);
  reinterpret_cast<float4*>(out)[i] = o;
}

__global__ void k_sentinel(float* out, float v) { out[0] = v; }

extern "C" void kernel_launch(void* const* d_in, const int* in_sizes, int n_in,
                              void* d_out, int out_size, void* d_ws, size_t ws_size,
                              hipStream_t stream) {
  // setup_inputs dict order: x, Wk, Wq, Wv, Wu
  const float* x  = (const float*)d_in[0];
  const float* Wk = (const float*)d_in[1];
  const float* Wq = (const float*)d_in[2];
  const float* Wv = (const float*)d_in[3];
  const float* Wu = (const float*)d_in[4];
  float* out = (float*)d_out;

  const long SZ_X = 4096L * 512;
  const size_t NEED = 150994944;  // 144 MiB

  if (ws_size < NEED) {
    hipMemsetAsync(d_out, 0, (size_t)out_size * 4, stream);
    k_sentinel<<<1, 1, 0, stream>>>(out, (float)ws_size);
    return;
  }

  char* p = (char*)d_ws;
  unsigned short* Xbf  = (unsigned short*)p; p += SZ_X * 2;           //  4 MiB
  unsigned short* Wvut = (unsigned short*)p; p += 8L * 512 * 512 * 2; //  4 MiB [h][e][k]
  unsigned short* Gt   = (unsigned short*)p; p += 8L * 512 * 512 * 2; //  4 MiB [h][b'][a]
  unsigned short* T    = (unsigned short*)p; p += 4096L * 4096 * 2;   // 32 MiB [bt][h*512+b']
  unsigned short* Pb   = (unsigned short*)p; p += 4096L * 8192 * 2;   // 64 MiB [b][i][h*1024+j]
  unsigned short* VUt  = (unsigned short*)p;                          // 32 MiB [h*512+e][b*1024+j]
  float* Opart = (float*)T;  // 32 MiB alias: T dead after S-gemm; 4x[4096][512] fp32

  // L1: x convert + weight folds (fp32-direct staging), one launch
  k_wsetup<<<dim3(8, 288), 256, 0, stream>>>(x, Wq, Wk, Wv, Wu, Xbf, Gt, Wvut);

  // L2: T = X.Gt^T (17.2 GF) + VU^T = Wvut.X^T (17.2 GF), fused
  k_gemm_tv<<<dim3(8, 256), 256, 0, stream>>>(Xbf, Gt, Wvut, T, VUt);

  // L3: P[b][i][h*1024+j] = T.X^T (34.4 GF), B-operand = X (L2-tiny)
  k_gemm_s<<<dim3(8, 256), 256, 0, stream>>>(Xbf, T, Pb);

  // L4: softmax over each 1024-chunk of P, in place
  k_softmax_x<<<dim3(8, 1024), 256, 0, stream>>>(Pb);

  // L5: out partials = P . VU^T (strided-head B), plain fp32 stores
  k_gemm_out<<<dim3(8, 64), 256, 0, stream>>>(Pb, VUt, Opart);

  // L6: out = sum of 4 partials
  k_reduce<<<2048, 256, 0, stream>>>(Opart, out);
}